// Round 15
// baseline (288.909 us; speedup 1.0000x reference)
//
#include <hip/hip_runtime.h>

#define DEVINL __device__ __forceinline__

typedef _Float16 half8 __attribute__((ext_vector_type(8)));
typedef _Float16 half4 __attribute__((ext_vector_type(4)));
typedef __fp16 fp16x2 __attribute__((ext_vector_type(2)));
typedef float f32x4 __attribute__((ext_vector_type(4)));
typedef float float4v __attribute__((ext_vector_type(4)));

static constexpr int kDIM = 1024;
static constexpr int kHEADS = 16;
static constexpr int kHD = 64;
static constexpr int kBS = 4;
static constexpr int kSQ = 2048;
static constexpr int kSK = 2048;
static constexpr int kMTOT = kBS * kSQ;  // 8192

DEVINL void async_copy16(void* lds, const void* g) {
  __builtin_amdgcn_global_load_lds(
      (__attribute__((address_space(1))) unsigned int*)(g),
      (__attribute__((address_space(3))) unsigned int*)(lds), 16, 0, 0);
}

DEVINL unsigned pkrtz_u32(float a, float b) {
  fp16x2 h = __builtin_amdgcn_cvt_pkrtz(a, b);
  unsigned u;
  __builtin_memcpy(&u, &h, 4);
  return u;
}

// ---------------- prep: mask bit-packing + weight f32->f16 (one launch) ---
__global__ void prep_kernel(const int* __restrict__ mask,
                            unsigned* __restrict__ bits,
                            const float* __restrict__ s0, const float* __restrict__ s1,
                            const float* __restrict__ s2, const float* __restrict__ s3,
                            _Float16* __restrict__ d0, _Float16* __restrict__ d1,
                            _Float16* __restrict__ d2, _Float16* __restrict__ d3) {
  int bid = blockIdx.x;
  if (bid < 2048) {
    int t = bid * 256 + threadIdx.x;  // word index
    const int4* p = (const int4*)(mask + (size_t)t * 32);
    unsigned w = 0;
#pragma unroll
    for (int j = 0; j < 8; ++j) {
      int4 v = p[j];
      w |= (v.x != 0 ? 1u : 0u) << (j * 4);
      w |= (v.y != 0 ? 1u : 0u) << (j * 4 + 1);
      w |= (v.z != 0 ? 1u : 0u) << (j * 4 + 2);
      w |= (v.w != 0 ? 1u : 0u) << (j * 4 + 3);
    }
    bits[t] = w;
  } else {
    int cb = bid - 2048;
    int which = cb >> 9;  // 512 blocks per 1M-elem matrix
    const float* s = which == 0 ? s0 : which == 1 ? s1 : which == 2 ? s2 : s3;
    _Float16* d = which == 0 ? d0 : which == 1 ? d1 : which == 2 ? d2 : d3;
    int j = ((cb & 511) * 256 + threadIdx.x) * 8;
    float4v a0 = *(const float4v*)(s + j);
    float4v a1 = *(const float4v*)(s + j + 4);
    half8 h;
    h[0] = (_Float16)a0[0]; h[1] = (_Float16)a0[1];
    h[2] = (_Float16)a0[2]; h[3] = (_Float16)a0[3];
    h[4] = (_Float16)a1[0]; h[5] = (_Float16)a1[1];
    h[6] = (_Float16)a1[2]; h[7] = (_Float16)a1[3];
    *(half8*)(d + j) = h;
  }
}

// ---------------- GEMM body: C[M,N] = A[M,K] @ B[N,K]^T + bias ------------
// 128x128 tile, BK=64, 4 waves (2x2), single buf, bm-fastest bid (XCD affine).
template <bool A_F32, bool OUT_F16>
DEVINL void gemm_body(const void* __restrict__ Aptr,
                      const _Float16* __restrict__ B,
                      const float* __restrict__ bias,
                      void* __restrict__ Cptr, int N, int K, int bid,
                      _Float16* As, _Float16* Bs) {
  const int tid = threadIdx.x;
  const int lane = tid & 63;
  const int w = tid >> 6;
  const int wr = w >> 1, wc = w & 1;
  const int bm0 = (bid & 63) << 7;  // M-tile fastest -> XCD = bm%8
  const int bn0 = (bid >> 6) << 7;
  const int c16 = lane & 15;
  const int hi4 = lane >> 4;

  f32x4 acc[4][4] = {};

  for (int k0 = 0; k0 < K; k0 += 64) {
    __syncthreads();
    // ---- stage A tile [128][64] f16, rows 128B, 8 segs, xor (row&7) ------
    if (A_F32) {
      const float* A32 = (const float*)Aptr;
#pragma unroll
      for (int i = 0; i < 4; ++i) {
        int c = i * 256 + tid;
        int row = c >> 3, seg = c & 7;
        int gseg = seg ^ (row & 7);
        const float* src = A32 + (size_t)(bm0 + row) * K + k0 + gseg * 8;
        float4v a0 = *(const float4v*)src;
        float4v a1 = *(const float4v*)(src + 4);
        half8 h;
        h[0] = (_Float16)a0[0]; h[1] = (_Float16)a0[1];
        h[2] = (_Float16)a0[2]; h[3] = (_Float16)a0[3];
        h[4] = (_Float16)a1[0]; h[5] = (_Float16)a1[1];
        h[6] = (_Float16)a1[2]; h[7] = (_Float16)a1[3];
        *(half8*)((char*)As + c * 16) = h;
      }
    } else {
      const _Float16* A16 = (const _Float16*)Aptr;
#pragma unroll
      for (int i = 0; i < 4; ++i) {
        int c = i * 256 + tid;
        int row = c >> 3, seg = c & 7;
        int gseg = seg ^ (row & 7);
        async_copy16((char*)As + i * 4096 + w * 1024,
                     A16 + (size_t)(bm0 + row) * K + k0 + gseg * 8);
      }
    }
    // ---- stage B tile ----------------------------------------------------
#pragma unroll
    for (int i = 0; i < 4; ++i) {
      int c = i * 256 + tid;
      int row = c >> 3, seg = c & 7;
      int gseg = seg ^ (row & 7);
      async_copy16((char*)Bs + i * 4096 + w * 1024,
                   B + (size_t)(bn0 + row) * K + k0 + gseg * 8);
    }
    __syncthreads();
    // ---- fragments + MFMA, per kf half (K=32 each) -----------------------
#pragma unroll
    for (int kf = 0; kf < 2; ++kf) {
      half8 af[4], bf[4];
#pragma unroll
      for (int m = 0; m < 4; ++m) {
        int row = wr * 64 + m * 16 + c16;
        int off = row * 128 + (((kf * 4 + hi4) << 4) ^ ((row & 7) << 4));
        af[m] = *(const half8*)((const char*)As + off);
      }
#pragma unroll
      for (int n = 0; n < 4; ++n) {
        int row = wc * 64 + n * 16 + c16;
        int off = row * 128 + (((kf * 4 + hi4) << 4) ^ ((row & 7) << 4));
        bf[n] = *(const half8*)((const char*)Bs + off);
      }
#pragma unroll
      for (int m = 0; m < 4; ++m)
#pragma unroll
        for (int n = 0; n < 4; ++n)
          acc[m][n] =
              __builtin_amdgcn_mfma_f32_16x16x32_f16(af[m], bf[n], acc[m][n], 0, 0, 0);
    }
  }
  // ---- epilogue: bias + store ------------------------------------------
#pragma unroll
  for (int n = 0; n < 4; ++n) {
    int col = bn0 + wc * 64 + n * 16 + c16;
    float bv = bias[col];
#pragma unroll
    for (int m = 0; m < 4; ++m) {
      int row0 = bm0 + wr * 64 + m * 16 + (hi4 << 2);
#pragma unroll
      for (int r = 0; r < 4; ++r) {
        float v = acc[m][n][r] + bv;
        if (OUT_F16)
          ((_Float16*)Cptr)[(size_t)(row0 + r) * N + col] = (_Float16)v;
        else
          ((float*)Cptr)[(size_t)(row0 + r) * N + col] = v;
      }
    }
  }
}

// Q/K/V projections in ONE launch: grid 1536, which = bid>>9.
__launch_bounds__(256, 2)
__global__ void gemm_qkv_kernel(const float* __restrict__ xq,
                                const float* __restrict__ xk,
                                const float* __restrict__ xv,
                                const _Float16* __restrict__ Wq,
                                const _Float16* __restrict__ Wk,
                                const _Float16* __restrict__ Wv,
                                const float* __restrict__ bq,
                                const float* __restrict__ bk,
                                const float* __restrict__ bv,
                                _Float16* __restrict__ Q16,
                                _Float16* __restrict__ K16,
                                _Float16* __restrict__ V16) {
  __shared__ __align__(16) _Float16 As[128 * 64];
  __shared__ __align__(16) _Float16 Bs[128 * 64];
  int which = blockIdx.x >> 9;
  int bid = blockIdx.x & 511;
  const float* A = which == 0 ? xq : which == 1 ? xk : xv;
  const _Float16* B = which == 0 ? Wq : which == 1 ? Wk : Wv;
  const float* bias = which == 0 ? bq : which == 1 ? bk : bv;
  _Float16* C = which == 0 ? Q16 : which == 1 ? K16 : V16;
  gemm_body<true, true>(A, B, bias, C, kDIM, kDIM, bid, As, Bs);
}

// O-projection (f16 A, f32 out), single launch.
__launch_bounds__(256, 2)
__global__ void gemm_o_kernel(const _Float16* __restrict__ Z16,
                              const _Float16* __restrict__ Wo,
                              const float* __restrict__ bo,
                              float* __restrict__ out) {
  __shared__ __align__(16) _Float16 As[128 * 64];
  __shared__ __align__(16) _Float16 Bs[128 * 64];
  gemm_body<false, false>(Z16, Wo, bo, out, kDIM, kDIM, blockIdx.x, As, Bs);
}

// ---------------- V transpose: V[(b s)][h*64+d] -> Vt[(b h d)][s] ---------
__global__ void transpose_v_kernel(const _Float16* __restrict__ V,
                                   _Float16* __restrict__ Vt) {
  __shared__ _Float16 tile[64][72];
  int bh = blockIdx.y;
  int b = bh >> 4, h = bh & 15;
  int s0 = blockIdx.x * 64;
  int tid = threadIdx.x;
  {
    int s = tid >> 2, dseg = tid & 3;
    const half8* src =
        (const half8*)(V + (size_t)(b * kSK + s0 + s) * kDIM + h * 64 + dseg * 16);
    half8 v0 = src[0], v1 = src[1];
#pragma unroll
    for (int j = 0; j < 8; ++j) {
      tile[s][dseg * 16 + j] = v0[j];
      tile[s][dseg * 16 + 8 + j] = v1[j];
    }
  }
  __syncthreads();
  {
    int d = tid >> 2, sseg = tid & 3;
    half8 o0, o1;
#pragma unroll
    for (int j = 0; j < 8; ++j) {
      o0[j] = tile[sseg * 16 + j][d];
      o1[j] = tile[sseg * 16 + 8 + j][d];
    }
    half8* dst = (half8*)(Vt + ((size_t)(bh * 64 + d)) * kSK + s0 + sseg * 16);
    dst[0] = o0;
    dst[1] = o1;
  }
}

// ---------------- flash attention (P-in-register PV, 32KB LDS) ------------
// block: 128 q-rows, 4 waves (32 rows each), KT=64 keys/iter, KV dbuf.
// Swapped QK^T (16x16x32) -> lane q=c16, keys n*16+hi4*4+r in regs.
// PV via mfma_f32_16x16x16_f16: B-frag layout (col=c16, k=hi4*4+r) IS the
// S^T register layout -> P feeds PV directly (pkrtz pairs), no Ps LDS.
// A-frag = Vt 8B ds_read_b64 (row d=df*16+c16, keys hi4*4+r). Output Z^T:
// lane q=c16 (lane-local l-normalize), d=df*16+hi4*4+r -> packed 8B stores.
// LDS = K/V dbuf 32768 exactly -> 4 blocks/CU (2x waves vs Ps version).
__launch_bounds__(256, 4)
__global__ void attn_kernel(const _Float16* __restrict__ Q,
                            const _Float16* __restrict__ K,
                            const _Float16* __restrict__ Vt,
                            const unsigned* __restrict__ maskbits,
                            _Float16* __restrict__ Z) {
  __shared__ __align__(16) char smem[32768];  // [K0 8K][V0 8K][K1 8K][V1 8K]
  const int tid = threadIdx.x, lane = tid & 63, w = tid >> 6;
  const int bid = blockIdx.x;
  const int hb = bid & 63;  // (b,h) fastest -> XCD = hb%8
  const int b = hb >> 4, h = hb & 15;
  const int qt0 = (bid >> 6) * 128;
  const int c16 = lane & 15;
  const int hi4 = lane >> 4;
  const unsigned* mb = maskbits + (size_t)b * kSQ * (kSK / 32);

  // ---- stage Q tile [128][64] over dbuf region (32KB exactly) ------------
#pragma unroll
  for (int i = 0; i < 4; ++i) {
    int c = i * 256 + tid;
    int row = c >> 3, seg = c & 7;
    int gseg = seg ^ (row & 7);
    async_copy16(smem + i * 4096 + w * 1024,
                 Q + (size_t)(b * kSQ + qt0 + row) * kDIM + h * 64 + gseg * 8);
  }
  __syncthreads();
  half8 qf[2][2];
#pragma unroll
  for (int m = 0; m < 2; ++m)
#pragma unroll
    for (int kf = 0; kf < 2; ++kf) {
      int row = w * 32 + m * 16 + c16;
      int off = row * 128 + (((kf * 4 + hi4) << 4) ^ ((row & 7) << 4));
      qf[m][kf] = *(const half8*)(smem + off);
      qf[m][kf] *= (_Float16)0.18033688f;  // 0.125 * log2(e)
    }
  __syncthreads();  // all waves consumed Q before K/V overwrite

  // ---- hoisted loop-invariant addresses ----------------------------------
  int kb_off[2][4];
#pragma unroll
  for (int kf = 0; kf < 2; ++kf)
#pragma unroll
    for (int n = 0; n < 4; ++n) {
      int key = n * 16 + c16;
      kb_off[kf][n] = key * 128 + (((kf * 4 + hi4) << 4) ^ ((key & 7) << 4));
    }
  // V A-frag: row d=df*16+c16, byte n*32+hi4*8 (swizzle on 16B chunks)
  int va_off[4][4];
#pragma unroll
  for (int n = 0; n < 4; ++n)
#pragma unroll
    for (int df = 0; df < 4; ++df) {
      int d = df * 16 + c16;
      int t = n * 2 + (hi4 >> 1);
      va_off[n][df] = d * 128 + (((t ^ (d & 7)) << 4) | ((hi4 & 1) * 8));
    }

  // stage helper: K[64][64] + Vt[64][64] into buf (bufoff = 0 or 16384)
  auto stage_kv = [&](int bufoff, int ktt) {
#pragma unroll
    for (int i = 0; i < 2; ++i) {
      int c = i * 256 + tid;
      int row = c >> 3, seg = c & 7;
      int gseg = seg ^ (row & 7);
      async_copy16(smem + bufoff + i * 4096 + w * 1024,
                   K + (size_t)(b * kSK + ktt + row) * kDIM + h * 64 + gseg * 8);
    }
#pragma unroll
    for (int i = 0; i < 2; ++i) {
      int c = i * 256 + tid;
      int row = c >> 3, seg = c & 7;
      int gseg = seg ^ (row & 7);
      async_copy16(smem + bufoff + 8192 + i * 4096 + w * 1024,
                   Vt + (size_t)((b * kHEADS + h) * kHD + row) * kSK + ktt + gseg * 8);
    }
  };

  // prologue: tile 0
  unsigned long long mq_cur[2], mq_nxt[2];
  stage_kv(0, 0);
#pragma unroll
  for (int m2 = 0; m2 < 2; ++m2) {
    int q = qt0 + w * 32 + m2 * 16 + c16;
    mq_cur[m2] = *(const unsigned long long*)(mb + (size_t)q * (kSK / 32));
  }
  asm volatile("s_waitcnt vmcnt(0)" ::: "memory");
  __builtin_amdgcn_s_barrier();
  asm volatile("" ::: "memory");

  f32x4 zacc[2][4] = {};
  f32x4 lacc[2] = {};
  half4 ones4;
#pragma unroll
  for (int j = 0; j < 4; ++j) ones4[j] = (_Float16)1.0f;

  int cur = 0;
  for (int kt = 0; kt < kSK; kt += 64) {
    // ---- prefetch next tile ---------------------------------------------
    if (kt + 64 < kSK) {
      stage_kv((cur ^ 1) * 16384, kt + 64);
#pragma unroll
      for (int m2 = 0; m2 < 2; ++m2) {
        int q = qt0 + w * 32 + m2 * 16 + c16;
        mq_nxt[m2] = *(const unsigned long long*)(mb + (size_t)q * (kSK / 32) +
                                                  ((kt + 64) >> 5));
      }
    }
    const char* bufK = smem + cur * 16384;
    const char* bufV = bufK + 8192;

    // ---- QK^T swapped (16x16x32): lane q=c16, key = n*16+hi4*4+r ---------
    f32x4 s[2][4] = {};
    __builtin_amdgcn_s_setprio(1);
#pragma unroll
    for (int kf = 0; kf < 2; ++kf)
#pragma unroll
      for (int n = 0; n < 4; ++n) {
        half8 kb = *(const half8*)(bufK + kb_off[kf][n]);
        s[0][n] = __builtin_amdgcn_mfma_f32_16x16x32_f16(kb, qf[0][kf], s[0][n], 0, 0, 0);
        s[1][n] = __builtin_amdgcn_mfma_f32_16x16x32_f16(kb, qf[1][kf], s[1][n], 0, 0, 0);
      }
    __builtin_amdgcn_s_setprio(0);

    const unsigned lo0 = (unsigned)(mq_cur[0] >> (hi4 * 4));
    const unsigned hh0 = (unsigned)(mq_cur[0] >> (hi4 * 4 + 32));
    const unsigned lo1 = (unsigned)(mq_cur[1] >> (hi4 * 4));
    const unsigned hh1 = (unsigned)(mq_cur[1] >> (hi4 * 4 + 32));

    // ---- per 16-key chunk: softmax -> pb regs -> PV (no LDS roundtrip) ---
#pragma unroll
    for (int n = 0; n < 4; ++n) {
      const int base = (n & 1) * 16;
      half4 pb[2];
#pragma unroll
      for (int m2 = 0; m2 < 2; ++m2) {
        unsigned sel = (n < 2) ? (m2 ? lo1 : lo0) : (m2 ? hh1 : hh0);
        float p[4];
#pragma unroll
        for (int r = 0; r < 4; ++r) {
          float pv = __builtin_exp2f(s[m2][n][r]);
          int msk = __builtin_amdgcn_sbfe((int)sel, base + r, 1);  // 0 or -1
          pv = __uint_as_float(__float_as_uint(pv) & (unsigned)msk);
          p[r] = pv;
        }
        uint2 pu = {pkrtz_u32(p[0], p[1]), pkrtz_u32(p[2], p[3])};
        __builtin_memcpy(&pb[m2], &pu, 8);
      }
      // V fragments for this key chunk (8B each, shared by both m2)
      half4 va[4];
#pragma unroll
      for (int df = 0; df < 4; ++df)
        va[df] = *(const half4*)(bufV + va_off[n][df]);
      __builtin_amdgcn_s_setprio(1);
#pragma unroll
      for (int m2 = 0; m2 < 2; ++m2) {
        lacc[m2] = __builtin_amdgcn_mfma_f32_16x16x16f16(ones4, pb[m2], lacc[m2], 0, 0, 0);
#pragma unroll
        for (int df = 0; df < 4; ++df)
          zacc[m2][df] = __builtin_amdgcn_mfma_f32_16x16x16f16(va[df], pb[m2],
                                                               zacc[m2][df], 0, 0, 0);
      }
      __builtin_amdgcn_s_setprio(0);
    }

    asm volatile("s_waitcnt vmcnt(0)" ::: "memory");
    __builtin_amdgcn_s_barrier();
    asm volatile("" ::: "memory");
    mq_cur[0] = mq_nxt[0];
    mq_cur[1] = mq_nxt[1];
    cur ^= 1;
  }

  // ---- epilogue: normalize (l is lane-local: q=c16), packed 8B stores ----
#pragma unroll
  for (int m2 = 0; m2 < 2; ++m2) {
    float inv = 1.0f / lacc[m2][0];
    int q = qt0 + w * 32 + m2 * 16 + c16;
#pragma unroll
    for (int df = 0; df < 4; ++df) {
      uint2 zw = {pkrtz_u32(zacc[m2][df][0] * inv, zacc[m2][df][1] * inv),
                  pkrtz_u32(zacc[m2][df][2] * inv, zacc[m2][df][3] * inv)};
      *(uint2*)(Z + (size_t)(b * kSQ + q) * kDIM + h * 64 + df * 16 + hi4 * 4) = zw;
    }
  }
}

// -------------------------------------------------------------------------
extern "C" void kernel_launch(void* const* d_in, const int* in_sizes, int n_in,
                              void* d_out, int out_size, void* d_ws,
                              size_t ws_size, hipStream_t stream) {
  const float* x_q = (const float*)d_in[0];
  const float* x_k = (const float*)d_in[1];
  const float* x_v = (const float*)d_in[2];
  const int* mask = (const int*)d_in[3];
  const float* wq = (const float*)d_in[4];
  const float* bq = (const float*)d_in[5];
  const float* wk = (const float*)d_in[6];
  const float* bk = (const float*)d_in[7];
  const float* wv = (const float*)d_in[8];
  const float* bv = (const float*)d_in[9];
  const float* wo = (const float*)d_in[10];
  const float* bo = (const float*)d_in[11];

  const size_t W_ELEMS = (size_t)1024 * 1024;
  const size_t T_ELEMS = (size_t)kMTOT * kDIM;  // 8192*1024
  const size_t NEED = (4 * W_ELEMS + 5 * T_ELEMS) * 2 + (size_t)kBS * kSQ * (kSK / 32) * 4;
  if (ws_size < NEED) return;  // leaves output poisoned -> visible failure

  char* ws = (char*)d_ws;
  _Float16* Wq16 = (_Float16*)ws;
  _Float16* Wk16 = Wq16 + W_ELEMS;
  _Float16* Wv16 = Wk16 + W_ELEMS;
  _Float16* Wo16 = Wv16 + W_ELEMS;
  _Float16* Q16 = Wo16 + W_ELEMS;
  _Float16* K16 = Q16 + T_ELEMS;
  _Float16* V16 = K16 + T_ELEMS;
  _Float16* Vt16 = V16 + T_ELEMS;
  _Float16* Z16 = Vt16 + T_ELEMS;
  unsigned* mbits = (unsigned*)(Z16 + T_ELEMS);

  prep_kernel<<<4096, 256, 0, stream>>>(mask, mbits, wq, wk, wv, wo,
                                        Wq16, Wk16, Wv16, Wo16);

  gemm_qkv_kernel<<<1536, 256, 0, stream>>>(x_q, x_k, x_v, Wq16, Wk16, Wv16,
                                            bq, bk, bv, Q16, K16, V16);

  transpose_v_kernel<<<dim3(32, 64), 256, 0, stream>>>(V16, Vt16);

  attn_kernel<<<1024, 256, 0, stream>>>(Q16, K16, Vt16, mbits, Z16);

  gemm_o_kernel<<<512, 256, 0, stream>>>(Z16, Wo16, bo, (float*)d_out);
}

// Round 16
// 259.812 us; speedup vs baseline: 1.1120x; 1.1120x over previous
//
#include <hip/hip_runtime.h>

#define DEVINL __device__ __forceinline__

typedef _Float16 half8 __attribute__((ext_vector_type(8)));
typedef _Float16 half4 __attribute__((ext_vector_type(4)));
typedef __fp16 fp16x2 __attribute__((ext_vector_type(2)));
typedef float f32x4 __attribute__((ext_vector_type(4)));
typedef float float4v __attribute__((ext_vector_type(4)));

static constexpr int kDIM = 1024;
static constexpr int kHEADS = 16;
static constexpr int kHD = 64;
static constexpr int kBS = 4;
static constexpr int kSQ = 2048;
static constexpr int kSK = 2048;
static constexpr int kMTOT = kBS * kSQ;  // 8192

DEVINL void async_copy16(void* lds, const void* g) {
  __builtin_amdgcn_global_load_lds(
      (__attribute__((address_space(1))) unsigned int*)(g),
      (__attribute__((address_space(3))) unsigned int*)(lds), 16, 0, 0);
}

DEVINL unsigned pkrtz_u32(float a, float b) {
  fp16x2 h = __builtin_amdgcn_cvt_pkrtz(a, b);
  unsigned u;
  __builtin_memcpy(&u, &h, 4);
  return u;
}

// ---------------- prep: mask bit-packing + weight f32->f16 (one launch) ---
__global__ void prep_kernel(const int* __restrict__ mask,
                            unsigned* __restrict__ bits,
                            const float* __restrict__ s0, const float* __restrict__ s1,
                            const float* __restrict__ s2, const float* __restrict__ s3,
                            _Float16* __restrict__ d0, _Float16* __restrict__ d1,
                            _Float16* __restrict__ d2, _Float16* __restrict__ d3) {
  int bid = blockIdx.x;
  if (bid < 2048) {
    int t = bid * 256 + threadIdx.x;  // word index
    const int4* p = (const int4*)(mask + (size_t)t * 32);
    unsigned w = 0;
#pragma unroll
    for (int j = 0; j < 8; ++j) {
      int4 v = p[j];
      w |= (v.x != 0 ? 1u : 0u) << (j * 4);
      w |= (v.y != 0 ? 1u : 0u) << (j * 4 + 1);
      w |= (v.z != 0 ? 1u : 0u) << (j * 4 + 2);
      w |= (v.w != 0 ? 1u : 0u) << (j * 4 + 3);
    }
    bits[t] = w;
  } else {
    int cb = bid - 2048;
    int which = cb >> 9;  // 512 blocks per 1M-elem matrix
    const float* s = which == 0 ? s0 : which == 1 ? s1 : which == 2 ? s2 : s3;
    _Float16* d = which == 0 ? d0 : which == 1 ? d1 : which == 2 ? d2 : d3;
    int j = ((cb & 511) * 256 + threadIdx.x) * 8;
    float4v a0 = *(const float4v*)(s + j);
    float4v a1 = *(const float4v*)(s + j + 4);
    half8 h;
    h[0] = (_Float16)a0[0]; h[1] = (_Float16)a0[1];
    h[2] = (_Float16)a0[2]; h[3] = (_Float16)a0[3];
    h[4] = (_Float16)a1[0]; h[5] = (_Float16)a1[1];
    h[6] = (_Float16)a1[2]; h[7] = (_Float16)a1[3];
    *(half8*)(d + j) = h;
  }
}

// ---------------- GEMM body: C[M,N] = A[M,K] @ B[N,K]^T + bias ------------
// 128x128 tile, BK=64, 4 waves (2x2), single buf, bm-fastest bid (XCD affine).
// OUT_MODE: 0 = f32 row-major, 1 = f16 row-major, 2 = f16 V-transposed
// (Vt[(b*16+h)*64+dl][s] with h=col>>6, dl=col&63, s=row&2047, b=row>>11).
template <bool A_F32, int OUT_MODE>
DEVINL void gemm_body(const void* __restrict__ Aptr,
                      const _Float16* __restrict__ B,
                      const float* __restrict__ bias,
                      void* __restrict__ Cptr, int N, int K, int bid,
                      _Float16* As, _Float16* Bs) {
  const int tid = threadIdx.x;
  const int lane = tid & 63;
  const int w = tid >> 6;
  const int wr = w >> 1, wc = w & 1;
  const int bm0 = (bid & 63) << 7;  // M-tile fastest -> XCD = bm%8
  const int bn0 = (bid >> 6) << 7;
  const int c16 = lane & 15;
  const int hi4 = lane >> 4;

  f32x4 acc[4][4] = {};

  for (int k0 = 0; k0 < K; k0 += 64) {
    __syncthreads();
    // ---- stage A tile [128][64] f16, rows 128B, 8 segs, xor (row&7) ------
    if (A_F32) {
      const float* A32 = (const float*)Aptr;
#pragma unroll
      for (int i = 0; i < 4; ++i) {
        int c = i * 256 + tid;
        int row = c >> 3, seg = c & 7;
        int gseg = seg ^ (row & 7);
        const float* src = A32 + (size_t)(bm0 + row) * K + k0 + gseg * 8;
        float4v a0 = *(const float4v*)src;
        float4v a1 = *(const float4v*)(src + 4);
        half8 h;
        h[0] = (_Float16)a0[0]; h[1] = (_Float16)a0[1];
        h[2] = (_Float16)a0[2]; h[3] = (_Float16)a0[3];
        h[4] = (_Float16)a1[0]; h[5] = (_Float16)a1[1];
        h[6] = (_Float16)a1[2]; h[7] = (_Float16)a1[3];
        *(half8*)((char*)As + c * 16) = h;
      }
    } else {
      const _Float16* A16 = (const _Float16*)Aptr;
#pragma unroll
      for (int i = 0; i < 4; ++i) {
        int c = i * 256 + tid;
        int row = c >> 3, seg = c & 7;
        int gseg = seg ^ (row & 7);
        async_copy16((char*)As + i * 4096 + w * 1024,
                     A16 + (size_t)(bm0 + row) * K + k0 + gseg * 8);
      }
    }
    // ---- stage B tile ----------------------------------------------------
#pragma unroll
    for (int i = 0; i < 4; ++i) {
      int c = i * 256 + tid;
      int row = c >> 3, seg = c & 7;
      int gseg = seg ^ (row & 7);
      async_copy16((char*)Bs + i * 4096 + w * 1024,
                   B + (size_t)(bn0 + row) * K + k0 + gseg * 8);
    }
    __syncthreads();
    // ---- fragments + MFMA, per kf half (K=32 each) -----------------------
#pragma unroll
    for (int kf = 0; kf < 2; ++kf) {
      half8 af[4], bf[4];
#pragma unroll
      for (int m = 0; m < 4; ++m) {
        int row = wr * 64 + m * 16 + c16;
        int off = row * 128 + (((kf * 4 + hi4) << 4) ^ ((row & 7) << 4));
        af[m] = *(const half8*)((const char*)As + off);
      }
#pragma unroll
      for (int n = 0; n < 4; ++n) {
        int row = wc * 64 + n * 16 + c16;
        int off = row * 128 + (((kf * 4 + hi4) << 4) ^ ((row & 7) << 4));
        bf[n] = *(const half8*)((const char*)Bs + off);
      }
#pragma unroll
      for (int m = 0; m < 4; ++m)
#pragma unroll
        for (int n = 0; n < 4; ++n)
          acc[m][n] =
              __builtin_amdgcn_mfma_f32_16x16x32_f16(af[m], bf[n], acc[m][n], 0, 0, 0);
    }
  }
  // ---- epilogue: bias + store ------------------------------------------
#pragma unroll
  for (int n = 0; n < 4; ++n) {
    int col = bn0 + wc * 64 + n * 16 + c16;
    float bv = bias[col];
#pragma unroll
    for (int m = 0; m < 4; ++m) {
      int row0 = bm0 + wr * 64 + m * 16 + (hi4 << 2);
      if (OUT_MODE == 2) {
        // V-transposed: 4 consecutive s-positions -> one 8B half4 store
        int bb = row0 >> 11, s0v = row0 & 2047;
        int hh = col >> 6, dl = col & 63;
        half4 hv;
        hv[0] = (_Float16)(acc[m][n][0] + bv);
        hv[1] = (_Float16)(acc[m][n][1] + bv);
        hv[2] = (_Float16)(acc[m][n][2] + bv);
        hv[3] = (_Float16)(acc[m][n][3] + bv);
        *(half4*)((_Float16*)Cptr + ((size_t)((bb * 16 + hh) * 64 + dl)) * 2048 + s0v) = hv;
      } else {
#pragma unroll
        for (int r = 0; r < 4; ++r) {
          float v = acc[m][n][r] + bv;
          if (OUT_MODE == 1)
            ((_Float16*)Cptr)[(size_t)(row0 + r) * N + col] = (_Float16)v;
          else
            ((float*)Cptr)[(size_t)(row0 + r) * N + col] = v;
        }
      }
    }
  }
}

// Q/K/V projections in ONE launch: grid 1536, which = bid>>9.
// V (which==2) writes the transposed Vt layout directly -> no transpose kernel.
__launch_bounds__(256, 2)
__global__ void gemm_qkv_kernel(const float* __restrict__ xq,
                                const float* __restrict__ xk,
                                const float* __restrict__ xv,
                                const _Float16* __restrict__ Wq,
                                const _Float16* __restrict__ Wk,
                                const _Float16* __restrict__ Wv,
                                const float* __restrict__ bq,
                                const float* __restrict__ bk,
                                const float* __restrict__ bv,
                                _Float16* __restrict__ Q16,
                                _Float16* __restrict__ K16,
                                _Float16* __restrict__ Vt16) {
  __shared__ __align__(16) _Float16 As[128 * 64];
  __shared__ __align__(16) _Float16 Bs[128 * 64];
  int which = blockIdx.x >> 9;
  int bid = blockIdx.x & 511;
  if (which == 2) {
    gemm_body<true, 2>(xv, Wv, bv, Vt16, kDIM, kDIM, bid, As, Bs);
  } else {
    const float* A = which == 0 ? xq : xk;
    const _Float16* B = which == 0 ? Wq : Wk;
    const float* bias = which == 0 ? bq : bk;
    _Float16* C = which == 0 ? Q16 : K16;
    gemm_body<true, 1>(A, B, bias, C, kDIM, kDIM, bid, As, Bs);
  }
}

// O-projection (f16 A, f32 out), single launch.
__launch_bounds__(256, 2)
__global__ void gemm_o_kernel(const _Float16* __restrict__ Z16,
                              const _Float16* __restrict__ Wo,
                              const float* __restrict__ bo,
                              float* __restrict__ out) {
  __shared__ __align__(16) _Float16 As[128 * 64];
  __shared__ __align__(16) _Float16 Bs[128 * 64];
  gemm_body<false, 0>(Z16, Wo, bo, out, kDIM, kDIM, blockIdx.x, As, Bs);
}

// ---------------- flash attention (r14-proven: XCD-affine grid) -----------
// block: 128 q-rows, 4 waves (32 rows each), KT=64 keys/iter.
// 1-D grid, (b,h) fastest: all 16 q-tiles of one (b,h) share an XCD.
// Swapped QK^T -> lane holds q=c16, keys in regs. No-max exp2 softmax.
// l via ones-MFMA. Mask via sbfe sign-extend + AND. Ps stride 144.
__launch_bounds__(256, 3)
__global__ void attn_kernel(const _Float16* __restrict__ Q,
                            const _Float16* __restrict__ K,
                            const _Float16* __restrict__ Vt,
                            const unsigned* __restrict__ maskbits,
                            _Float16* __restrict__ Z) {
  __shared__ __align__(16) char smem[32768 + 128 * 72 * 2];  // 2 KV bufs + Ps
  _Float16* Ps = (_Float16*)(smem + 32768);                  // [128][72]
  const int tid = threadIdx.x, lane = tid & 63, w = tid >> 6;
  const int bid = blockIdx.x;
  const int hb = bid & 63;           // (b,h) fastest -> XCD = hb%8
  const int b = hb >> 4, h = hb & 15;
  const int qt0 = (bid >> 6) * 128;
  const int c16 = lane & 15;
  const int hi4 = lane >> 4;
  const int row4 = hi4 << 2;
  const unsigned* mb = maskbits + (size_t)b * kSQ * (kSK / 32);

  // ---- stage Q tile [128][64] into buf region ---------------------------
#pragma unroll
  for (int i = 0; i < 4; ++i) {
    int c = i * 256 + tid;
    int row = c >> 3, seg = c & 7;
    int gseg = seg ^ (row & 7);
    async_copy16(smem + i * 4096 + w * 1024,
                 Q + (size_t)(b * kSQ + qt0 + row) * kDIM + h * 64 + gseg * 8);
  }
  __syncthreads();
  half8 qf[2][2];
#pragma unroll
  for (int m = 0; m < 2; ++m)
#pragma unroll
    for (int kf = 0; kf < 2; ++kf) {
      int row = w * 32 + m * 16 + c16;
      int off = row * 128 + (((kf * 4 + hi4) << 4) ^ ((row & 7) << 4));
      qf[m][kf] = *(const half8*)(smem + off);
      qf[m][kf] *= (_Float16)0.18033688f;  // 0.125 * log2(e)
    }
  __syncthreads();  // all waves consumed Q before K/V overwrite

  // stage helper: K[64][64] + Vt[64][64] into buf (bufoff = 0 or 16384)
  auto stage_kv = [&](int bufoff, int ktt) {
#pragma unroll
    for (int i = 0; i < 2; ++i) {
      int c = i * 256 + tid;
      int row = c >> 3, seg = c & 7;
      int gseg = seg ^ (row & 7);
      async_copy16(smem + bufoff + i * 4096 + w * 1024,
                   K + (size_t)(b * kSK + ktt + row) * kDIM + h * 64 + gseg * 8);
    }
#pragma unroll
    for (int i = 0; i < 2; ++i) {
      int c = i * 256 + tid;
      int row = c >> 3, seg = c & 7;
      int gseg = seg ^ (row & 7);
      async_copy16(smem + bufoff + 8192 + i * 4096 + w * 1024,
                   Vt + (size_t)((b * kHEADS + h) * kHD + row) * kSK + ktt + gseg * 8);
    }
  };

  // prologue: tile 0
  unsigned long long mq_cur[2], mq_nxt[2];
  stage_kv(0, 0);
#pragma unroll
  for (int m2 = 0; m2 < 2; ++m2) {
    int q = qt0 + w * 32 + m2 * 16 + c16;
    mq_cur[m2] = *(const unsigned long long*)(mb + (size_t)q * (kSK / 32));
  }
  asm volatile("s_waitcnt vmcnt(0)" ::: "memory");
  __builtin_amdgcn_s_barrier();
  asm volatile("" ::: "memory");

  f32x4 zacc[2][4] = {};
  f32x4 lacc[2] = {};
  half8 ones8;
#pragma unroll
  for (int j = 0; j < 8; ++j) ones8[j] = (_Float16)1.0f;

  int cur = 0;
  for (int kt = 0; kt < kSK; kt += 64) {
    // ---- prefetch next tile ---------------------------------------------
    if (kt + 64 < kSK) {
      stage_kv((cur ^ 1) * 16384, kt + 64);
#pragma unroll
      for (int m2 = 0; m2 < 2; ++m2) {
        int q = qt0 + w * 32 + m2 * 16 + c16;
        mq_nxt[m2] = *(const unsigned long long*)(mb + (size_t)q * (kSK / 32) +
                                                  ((kt + 64) >> 5));
      }
    }
    const char* bufK = smem + cur * 16384;
    const char* bufV = bufK + 8192;

    // ---- QK^T swapped: lane q=c16, key = n*16 + hi4*4 + r ----------------
    f32x4 s[2][4] = {};
    __builtin_amdgcn_s_setprio(1);
#pragma unroll
    for (int kf = 0; kf < 2; ++kf)
#pragma unroll
      for (int n = 0; n < 4; ++n) {
        int key = n * 16 + c16;
        half8 kb = *(const half8*)(bufK + key * 128 +
                                   (((kf * 4 + hi4) << 4) ^ ((key & 7) << 4)));
        s[0][n] = __builtin_amdgcn_mfma_f32_16x16x32_f16(kb, qf[0][kf], s[0][n], 0, 0, 0);
        s[1][n] = __builtin_amdgcn_mfma_f32_16x16x32_f16(kb, qf[1][kf], s[1][n], 0, 0, 0);
      }
    __builtin_amdgcn_s_setprio(0);

    // ---- softmax: P = 2^s AND sbfe-mask (no max; s bounded) --------------
#pragma unroll
    for (int m2 = 0; m2 < 2; ++m2) {
      unsigned lo = (unsigned)(mq_cur[m2] >> (hi4 * 4));
      unsigned hh = (unsigned)(mq_cur[m2] >> (hi4 * 4 + 32));
      int q_local = w * 32 + m2 * 16 + c16;
#pragma unroll
      for (int n = 0; n < 4; ++n) {
        unsigned sel = (n < 2) ? lo : hh;
        const int base = (n & 1) * 16;
        float p[4];
#pragma unroll
        for (int r = 0; r < 4; ++r) {
          float pv = __builtin_exp2f(s[m2][n][r]);
          int msk = __builtin_amdgcn_sbfe((int)sel, base + r, 1);  // 0 or -1
          pv = __uint_as_float(__float_as_uint(pv) & (unsigned)msk);
          p[r] = pv;
        }
        uint2 pw = {pkrtz_u32(p[0], p[1]), pkrtz_u32(p[2], p[3])};
        *(uint2*)((char*)Ps + q_local * 144 + n * 32 + hi4 * 8) = pw;
      }
    }

    // ---- PV + l-accum (ones-MFMA) ---------------------------------------
    __builtin_amdgcn_s_setprio(1);
#pragma unroll
    for (int kf2 = 0; kf2 < 2; ++kf2) {
      half8 vb[4];
#pragma unroll
      for (int df = 0; df < 4; ++df) {
        int d = df * 16 + c16;
        vb[df] = *(const half8*)(bufV + d * 128 +
                                 (((kf2 * 4 + hi4) << 4) ^ ((d & 7) << 4)));
      }
#pragma unroll
      for (int m2 = 0; m2 < 2; ++m2) {
        int q_local = w * 32 + m2 * 16 + c16;
        half8 pa = *(const half8*)((char*)Ps + q_local * 144 + (kf2 * 4 + hi4) * 16);
        lacc[m2] = __builtin_amdgcn_mfma_f32_16x16x32_f16(pa, ones8, lacc[m2], 0, 0, 0);
#pragma unroll
        for (int df = 0; df < 4; ++df)
          zacc[m2][df] =
              __builtin_amdgcn_mfma_f32_16x16x32_f16(pa, vb[df], zacc[m2][df], 0, 0, 0);
      }
    }
    __builtin_amdgcn_s_setprio(0);

    asm volatile("s_waitcnt vmcnt(0)" ::: "memory");
    __builtin_amdgcn_s_barrier();
    asm volatile("" ::: "memory");
    mq_cur[0] = mq_nxt[0];
    mq_cur[1] = mq_nxt[1];
    cur ^= 1;
  }

  // ---- epilogue: normalize (lacc rows match zacc rows), write Z ----------
#pragma unroll
  for (int m2 = 0; m2 < 2; ++m2)
#pragma unroll
    for (int r = 0; r < 4; ++r) {
      float inv = 1.0f / lacc[m2][r];
      int q = qt0 + w * 32 + m2 * 16 + row4 + r;
#pragma unroll
      for (int df = 0; df < 4; ++df) {
        int d = df * 16 + c16;
        Z[(size_t)(b * kSQ + q) * kDIM + h * 64 + d] =
            (_Float16)(zacc[m2][df][r] * inv);
      }
    }
}

// -------------------------------------------------------------------------
extern "C" void kernel_launch(void* const* d_in, const int* in_sizes, int n_in,
                              void* d_out, int out_size, void* d_ws,
                              size_t ws_size, hipStream_t stream) {
  const float* x_q = (const float*)d_in[0];
  const float* x_k = (const float*)d_in[1];
  const float* x_v = (const float*)d_in[2];
  const int* mask = (const int*)d_in[3];
  const float* wq = (const float*)d_in[4];
  const float* bq = (const float*)d_in[5];
  const float* wk = (const float*)d_in[6];
  const float* bk = (const float*)d_in[7];
  const float* wv = (const float*)d_in[8];
  const float* bv = (const float*)d_in[9];
  const float* wo = (const float*)d_in[10];
  const float* bo = (const float*)d_in[11];

  const size_t W_ELEMS = (size_t)1024 * 1024;
  const size_t T_ELEMS = (size_t)kMTOT * kDIM;  // 8192*1024
  const size_t NEED = (4 * W_ELEMS + 5 * T_ELEMS) * 2 + (size_t)kBS * kSQ * (kSK / 32) * 4;
  if (ws_size < NEED) return;  // leaves output poisoned -> visible failure

  char* ws = (char*)d_ws;
  _Float16* Wq16 = (_Float16*)ws;
  _Float16* Wk16 = Wq16 + W_ELEMS;
  _Float16* Wv16 = Wk16 + W_ELEMS;
  _Float16* Wo16 = Wv16 + W_ELEMS;
  _Float16* Q16 = Wo16 + W_ELEMS;
  _Float16* K16 = Q16 + T_ELEMS;
  _Float16* V16 = K16 + T_ELEMS;   // unused (V written transposed directly)
  _Float16* Vt16 = V16 + T_ELEMS;
  _Float16* Z16 = Vt16 + T_ELEMS;
  unsigned* mbits = (unsigned*)(Z16 + T_ELEMS);

  prep_kernel<<<4096, 256, 0, stream>>>(mask, mbits, wq, wk, wv, wo,
                                        Wq16, Wk16, Wv16, Wo16);

  gemm_qkv_kernel<<<1536, 256, 0, stream>>>(x_q, x_k, x_v, Wq16, Wk16, Wv16,
                                            bq, bk, bv, Q16, K16, Vt16);

  attn_kernel<<<1024, 256, 0, stream>>>(Q16, K16, Vt16, mbits, Z16);

  gemm_o_kernel<<<512, 256, 0, stream>>>(Z16, Wo16, bo, (float*)d_out);
}

// Round 17
// 257.002 us; speedup vs baseline: 1.1241x; 1.0109x over previous
//
#include <hip/hip_runtime.h>

#define DEVINL __device__ __forceinline__

typedef _Float16 half8 __attribute__((ext_vector_type(8)));
typedef _Float16 half4 __attribute__((ext_vector_type(4)));
typedef __fp16 fp16x2 __attribute__((ext_vector_type(2)));
typedef float f32x4 __attribute__((ext_vector_type(4)));
typedef float float4v __attribute__((ext_vector_type(4)));

static constexpr int kDIM = 1024;
static constexpr int kHEADS = 16;
static constexpr int kHD = 64;
static constexpr int kBS = 4;
static constexpr int kSQ = 2048;
static constexpr int kSK = 2048;
static constexpr int kMTOT = kBS * kSQ;  // 8192

DEVINL void async_copy16(void* lds, const void* g) {
  __builtin_amdgcn_global_load_lds(
      (__attribute__((address_space(1))) unsigned int*)(g),
      (__attribute__((address_space(3))) unsigned int*)(lds), 16, 0, 0);
}

DEVINL unsigned pkrtz_u32(float a, float b) {
  fp16x2 h = __builtin_amdgcn_cvt_pkrtz(a, b);
  unsigned u;
  __builtin_memcpy(&u, &h, 4);
  return u;
}

// ---------------- prep: mask bit-packing + weight f32->f16 (one launch) ---
__global__ void prep_kernel(const int* __restrict__ mask,
                            unsigned* __restrict__ bits,
                            const float* __restrict__ s0, const float* __restrict__ s1,
                            const float* __restrict__ s2, const float* __restrict__ s3,
                            _Float16* __restrict__ d0, _Float16* __restrict__ d1,
                            _Float16* __restrict__ d2, _Float16* __restrict__ d3) {
  int bid = blockIdx.x;
  if (bid < 2048) {
    int t = bid * 256 + threadIdx.x;  // word index
    const int4* p = (const int4*)(mask + (size_t)t * 32);
    unsigned w = 0;
#pragma unroll
    for (int j = 0; j < 8; ++j) {
      int4 v = p[j];
      w |= (v.x != 0 ? 1u : 0u) << (j * 4);
      w |= (v.y != 0 ? 1u : 0u) << (j * 4 + 1);
      w |= (v.z != 0 ? 1u : 0u) << (j * 4 + 2);
      w |= (v.w != 0 ? 1u : 0u) << (j * 4 + 3);
    }
    bits[t] = w;
  } else {
    int cb = bid - 2048;
    int which = cb >> 9;  // 512 blocks per 1M-elem matrix
    const float* s = which == 0 ? s0 : which == 1 ? s1 : which == 2 ? s2 : s3;
    _Float16* d = which == 0 ? d0 : which == 1 ? d1 : which == 2 ? d2 : d3;
    int j = ((cb & 511) * 256 + threadIdx.x) * 8;
    float4v a0 = *(const float4v*)(s + j);
    float4v a1 = *(const float4v*)(s + j + 4);
    half8 h;
    h[0] = (_Float16)a0[0]; h[1] = (_Float16)a0[1];
    h[2] = (_Float16)a0[2]; h[3] = (_Float16)a0[3];
    h[4] = (_Float16)a1[0]; h[5] = (_Float16)a1[1];
    h[6] = (_Float16)a1[2]; h[7] = (_Float16)a1[3];
    *(half8*)(d + j) = h;
  }
}

// ---------------- GEMM body: C[M,N] = A[M,K] @ B[N,K]^T + bias ------------
// 128x128 tile, BK=64, 4 waves (2x2), single buf, bm-fastest bid (XCD affine).
template <bool A_F32, bool OUT_F16>
DEVINL void gemm_body(const void* __restrict__ Aptr,
                      const _Float16* __restrict__ B,
                      const float* __restrict__ bias,
                      void* __restrict__ Cptr, int N, int K, int bid,
                      _Float16* As, _Float16* Bs) {
  const int tid = threadIdx.x;
  const int lane = tid & 63;
  const int w = tid >> 6;
  const int wr = w >> 1, wc = w & 1;
  const int bm0 = (bid & 63) << 7;  // M-tile fastest -> XCD = bm%8
  const int bn0 = (bid >> 6) << 7;
  const int c16 = lane & 15;
  const int hi4 = lane >> 4;

  f32x4 acc[4][4] = {};

  for (int k0 = 0; k0 < K; k0 += 64) {
    __syncthreads();
    // ---- stage A tile [128][64] f16, rows 128B, 8 segs, xor (row&7) ------
    if (A_F32) {
      const float* A32 = (const float*)Aptr;
#pragma unroll
      for (int i = 0; i < 4; ++i) {
        int c = i * 256 + tid;
        int row = c >> 3, seg = c & 7;
        int gseg = seg ^ (row & 7);
        const float* src = A32 + (size_t)(bm0 + row) * K + k0 + gseg * 8;
        float4v a0 = *(const float4v*)src;
        float4v a1 = *(const float4v*)(src + 4);
        half8 h;
        h[0] = (_Float16)a0[0]; h[1] = (_Float16)a0[1];
        h[2] = (_Float16)a0[2]; h[3] = (_Float16)a0[3];
        h[4] = (_Float16)a1[0]; h[5] = (_Float16)a1[1];
        h[6] = (_Float16)a1[2]; h[7] = (_Float16)a1[3];
        *(half8*)((char*)As + c * 16) = h;
      }
    } else {
      const _Float16* A16 = (const _Float16*)Aptr;
#pragma unroll
      for (int i = 0; i < 4; ++i) {
        int c = i * 256 + tid;
        int row = c >> 3, seg = c & 7;
        int gseg = seg ^ (row & 7);
        async_copy16((char*)As + i * 4096 + w * 1024,
                     A16 + (size_t)(bm0 + row) * K + k0 + gseg * 8);
      }
    }
    // ---- stage B tile ----------------------------------------------------
#pragma unroll
    for (int i = 0; i < 4; ++i) {
      int c = i * 256 + tid;
      int row = c >> 3, seg = c & 7;
      int gseg = seg ^ (row & 7);
      async_copy16((char*)Bs + i * 4096 + w * 1024,
                   B + (size_t)(bn0 + row) * K + k0 + gseg * 8);
    }
    __syncthreads();
    // ---- fragments + MFMA, per kf half (K=32 each) -----------------------
#pragma unroll
    for (int kf = 0; kf < 2; ++kf) {
      half8 af[4], bf[4];
#pragma unroll
      for (int m = 0; m < 4; ++m) {
        int row = wr * 64 + m * 16 + c16;
        int off = row * 128 + (((kf * 4 + hi4) << 4) ^ ((row & 7) << 4));
        af[m] = *(const half8*)((const char*)As + off);
      }
#pragma unroll
      for (int n = 0; n < 4; ++n) {
        int row = wc * 64 + n * 16 + c16;
        int off = row * 128 + (((kf * 4 + hi4) << 4) ^ ((row & 7) << 4));
        bf[n] = *(const half8*)((const char*)Bs + off);
      }
#pragma unroll
      for (int m = 0; m < 4; ++m)
#pragma unroll
        for (int n = 0; n < 4; ++n)
          acc[m][n] =
              __builtin_amdgcn_mfma_f32_16x16x32_f16(af[m], bf[n], acc[m][n], 0, 0, 0);
    }
  }
  // ---- epilogue: bias + store ------------------------------------------
#pragma unroll
  for (int n = 0; n < 4; ++n) {
    int col = bn0 + wc * 64 + n * 16 + c16;
    float bv = bias[col];
#pragma unroll
    for (int m = 0; m < 4; ++m) {
      int row0 = bm0 + wr * 64 + m * 16 + (hi4 << 2);
#pragma unroll
      for (int r = 0; r < 4; ++r) {
        float v = acc[m][n][r] + bv;
        if (OUT_F16)
          ((_Float16*)Cptr)[(size_t)(row0 + r) * N + col] = (_Float16)v;
        else
          ((float*)Cptr)[(size_t)(row0 + r) * N + col] = v;
      }
    }
  }
}

// Q/K/V projections in ONE launch: grid 1536, which = bid>>9.
__launch_bounds__(256, 2)
__global__ void gemm_qkv_kernel(const float* __restrict__ xq,
                                const float* __restrict__ xk,
                                const float* __restrict__ xv,
                                const _Float16* __restrict__ Wq,
                                const _Float16* __restrict__ Wk,
                                const _Float16* __restrict__ Wv,
                                const float* __restrict__ bq,
                                const float* __restrict__ bk,
                                const float* __restrict__ bv,
                                _Float16* __restrict__ Q16,
                                _Float16* __restrict__ K16,
                                _Float16* __restrict__ V16) {
  __shared__ __align__(16) _Float16 As[128 * 64];
  __shared__ __align__(16) _Float16 Bs[128 * 64];
  int which = blockIdx.x >> 9;
  int bid = blockIdx.x & 511;
  const float* A = which == 0 ? xq : which == 1 ? xk : xv;
  const _Float16* B = which == 0 ? Wq : which == 1 ? Wk : Wv;
  const float* bias = which == 0 ? bq : which == 1 ? bk : bv;
  _Float16* C = which == 0 ? Q16 : which == 1 ? K16 : V16;
  gemm_body<true, true>(A, B, bias, C, kDIM, kDIM, bid, As, Bs);
}

// O-projection (f16 A, f32 out), single launch.
__launch_bounds__(256, 2)
__global__ void gemm_o_kernel(const _Float16* __restrict__ Z16,
                              const _Float16* __restrict__ Wo,
                              const float* __restrict__ bo,
                              float* __restrict__ out) {
  __shared__ __align__(16) _Float16 As[128 * 64];
  __shared__ __align__(16) _Float16 Bs[128 * 64];
  gemm_body<false, false>(Z16, Wo, bo, out, kDIM, kDIM, blockIdx.x, As, Bs);
}

// ---------------- V transpose: V[(b s)][h*64+d] -> Vt[(b h d)][s] ---------
// 1-D grid, (b,h) fastest: transpose block for (b,h) runs on XCD bh%8 — the
// same XCD whose attn blocks consume that Vt (same mapping) -> warm L2.
__global__ void transpose_v_kernel(const _Float16* __restrict__ V,
                                   _Float16* __restrict__ Vt) {
  __shared__ _Float16 tile[64][72];
  int bid = blockIdx.x;
  int bh = bid & 63;  // (b,h) fastest -> XCD = bh%8 (matches attn)
  int b = bh >> 4, h = bh & 15;
  int s0 = (bid >> 6) * 64;
  int tid = threadIdx.x;
  {
    int s = tid >> 2, dseg = tid & 3;
    const half8* src =
        (const half8*)(V + (size_t)(b * kSK + s0 + s) * kDIM + h * 64 + dseg * 16);
    half8 v0 = src[0], v1 = src[1];
#pragma unroll
    for (int j = 0; j < 8; ++j) {
      tile[s][dseg * 16 + j] = v0[j];
      tile[s][dseg * 16 + 8 + j] = v1[j];
    }
  }
  __syncthreads();
  {
    int d = tid >> 2, sseg = tid & 3;
    half8 o0, o1;
#pragma unroll
    for (int j = 0; j < 8; ++j) {
      o0[j] = tile[sseg * 16 + j][d];
      o1[j] = tile[sseg * 16 + 8 + j][d];
    }
    half8* dst = (half8*)(Vt + ((size_t)(bh * 64 + d)) * kSK + s0 + sseg * 16);
    dst[0] = o0;
    dst[1] = o1;
  }
}

// ---------------- flash attention (r14-proven: XCD-affine grid) -----------
// block: 128 q-rows, 4 waves (32 rows each), KT=64 keys/iter.
// 1-D grid, (b,h) fastest: all 16 q-tiles of one (b,h) share an XCD.
// Swapped QK^T -> lane holds q=c16, keys in regs. No-max exp2 softmax.
// l via ones-MFMA. Mask via sbfe sign-extend + AND. Ps stride 144.
__launch_bounds__(256, 3)
__global__ void attn_kernel(const _Float16* __restrict__ Q,
                            const _Float16* __restrict__ K,
                            const _Float16* __restrict__ Vt,
                            const unsigned* __restrict__ maskbits,
                            _Float16* __restrict__ Z) {
  __shared__ __align__(16) char smem[32768 + 128 * 72 * 2];  // 2 KV bufs + Ps
  _Float16* Ps = (_Float16*)(smem + 32768);                  // [128][72]
  const int tid = threadIdx.x, lane = tid & 63, w = tid >> 6;
  const int bid = blockIdx.x;
  const int hb = bid & 63;           // (b,h) fastest -> XCD = hb%8
  const int b = hb >> 4, h = hb & 15;
  const int qt0 = (bid >> 6) * 128;
  const int c16 = lane & 15;
  const int hi4 = lane >> 4;
  const int row4 = hi4 << 2;
  const unsigned* mb = maskbits + (size_t)b * kSQ * (kSK / 32);

  // ---- stage Q tile [128][64] into buf region ---------------------------
#pragma unroll
  for (int i = 0; i < 4; ++i) {
    int c = i * 256 + tid;
    int row = c >> 3, seg = c & 7;
    int gseg = seg ^ (row & 7);
    async_copy16(smem + i * 4096 + w * 1024,
                 Q + (size_t)(b * kSQ + qt0 + row) * kDIM + h * 64 + gseg * 8);
  }
  __syncthreads();
  half8 qf[2][2];
#pragma unroll
  for (int m = 0; m < 2; ++m)
#pragma unroll
    for (int kf = 0; kf < 2; ++kf) {
      int row = w * 32 + m * 16 + c16;
      int off = row * 128 + (((kf * 4 + hi4) << 4) ^ ((row & 7) << 4));
      qf[m][kf] = *(const half8*)(smem + off);
      qf[m][kf] *= (_Float16)0.18033688f;  // 0.125 * log2(e)
    }
  __syncthreads();  // all waves consumed Q before K/V overwrite

  // stage helper: K[64][64] + Vt[64][64] into buf (bufoff = 0 or 16384)
  auto stage_kv = [&](int bufoff, int ktt) {
#pragma unroll
    for (int i = 0; i < 2; ++i) {
      int c = i * 256 + tid;
      int row = c >> 3, seg = c & 7;
      int gseg = seg ^ (row & 7);
      async_copy16(smem + bufoff + i * 4096 + w * 1024,
                   K + (size_t)(b * kSK + ktt + row) * kDIM + h * 64 + gseg * 8);
    }
#pragma unroll
    for (int i = 0; i < 2; ++i) {
      int c = i * 256 + tid;
      int row = c >> 3, seg = c & 7;
      int gseg = seg ^ (row & 7);
      async_copy16(smem + bufoff + 8192 + i * 4096 + w * 1024,
                   Vt + (size_t)((b * kHEADS + h) * kHD + row) * kSK + ktt + gseg * 8);
    }
  };

  // prologue: tile 0
  unsigned long long mq_cur[2], mq_nxt[2];
  stage_kv(0, 0);
#pragma unroll
  for (int m2 = 0; m2 < 2; ++m2) {
    int q = qt0 + w * 32 + m2 * 16 + c16;
    mq_cur[m2] = *(const unsigned long long*)(mb + (size_t)q * (kSK / 32));
  }
  asm volatile("s_waitcnt vmcnt(0)" ::: "memory");
  __builtin_amdgcn_s_barrier();
  asm volatile("" ::: "memory");

  f32x4 zacc[2][4] = {};
  f32x4 lacc[2] = {};
  half8 ones8;
#pragma unroll
  for (int j = 0; j < 8; ++j) ones8[j] = (_Float16)1.0f;

  int cur = 0;
  for (int kt = 0; kt < kSK; kt += 64) {
    // ---- prefetch next tile ---------------------------------------------
    if (kt + 64 < kSK) {
      stage_kv((cur ^ 1) * 16384, kt + 64);
#pragma unroll
      for (int m2 = 0; m2 < 2; ++m2) {
        int q = qt0 + w * 32 + m2 * 16 + c16;
        mq_nxt[m2] = *(const unsigned long long*)(mb + (size_t)q * (kSK / 32) +
                                                  ((kt + 64) >> 5));
      }
    }
    const char* bufK = smem + cur * 16384;
    const char* bufV = bufK + 8192;

    // ---- QK^T swapped: lane q=c16, key = n*16 + hi4*4 + r ----------------
    f32x4 s[2][4] = {};
    __builtin_amdgcn_s_setprio(1);
#pragma unroll
    for (int kf = 0; kf < 2; ++kf)
#pragma unroll
      for (int n = 0; n < 4; ++n) {
        int key = n * 16 + c16;
        half8 kb = *(const half8*)(bufK + key * 128 +
                                   (((kf * 4 + hi4) << 4) ^ ((key & 7) << 4)));
        s[0][n] = __builtin_amdgcn_mfma_f32_16x16x32_f16(kb, qf[0][kf], s[0][n], 0, 0, 0);
        s[1][n] = __builtin_amdgcn_mfma_f32_16x16x32_f16(kb, qf[1][kf], s[1][n], 0, 0, 0);
      }
    __builtin_amdgcn_s_setprio(0);

    // ---- softmax: P = 2^s AND sbfe-mask (no max; s bounded) --------------
#pragma unroll
    for (int m2 = 0; m2 < 2; ++m2) {
      unsigned lo = (unsigned)(mq_cur[m2] >> (hi4 * 4));
      unsigned hh = (unsigned)(mq_cur[m2] >> (hi4 * 4 + 32));
      int q_local = w * 32 + m2 * 16 + c16;
#pragma unroll
      for (int n = 0; n < 4; ++n) {
        unsigned sel = (n < 2) ? lo : hh;
        const int base = (n & 1) * 16;
        float p[4];
#pragma unroll
        for (int r = 0; r < 4; ++r) {
          float pv = __builtin_exp2f(s[m2][n][r]);
          int msk = __builtin_amdgcn_sbfe((int)sel, base + r, 1);  // 0 or -1
          pv = __uint_as_float(__float_as_uint(pv) & (unsigned)msk);
          p[r] = pv;
        }
        uint2 pw = {pkrtz_u32(p[0], p[1]), pkrtz_u32(p[2], p[3])};
        *(uint2*)((char*)Ps + q_local * 144 + n * 32 + hi4 * 8) = pw;
      }
    }

    // ---- PV + l-accum (ones-MFMA) ---------------------------------------
    __builtin_amdgcn_s_setprio(1);
#pragma unroll
    for (int kf2 = 0; kf2 < 2; ++kf2) {
      half8 vb[4];
#pragma unroll
      for (int df = 0; df < 4; ++df) {
        int d = df * 16 + c16;
        vb[df] = *(const half8*)(bufV + d * 128 +
                                 (((kf2 * 4 + hi4) << 4) ^ ((d & 7) << 4)));
      }
#pragma unroll
      for (int m2 = 0; m2 < 2; ++m2) {
        int q_local = w * 32 + m2 * 16 + c16;
        half8 pa = *(const half8*)((char*)Ps + q_local * 144 + (kf2 * 4 + hi4) * 16);
        lacc[m2] = __builtin_amdgcn_mfma_f32_16x16x32_f16(pa, ones8, lacc[m2], 0, 0, 0);
#pragma unroll
        for (int df = 0; df < 4; ++df)
          zacc[m2][df] =
              __builtin_amdgcn_mfma_f32_16x16x32_f16(pa, vb[df], zacc[m2][df], 0, 0, 0);
      }
    }
    __builtin_amdgcn_s_setprio(0);

    asm volatile("s_waitcnt vmcnt(0)" ::: "memory");
    __builtin_amdgcn_s_barrier();
    asm volatile("" ::: "memory");
    mq_cur[0] = mq_nxt[0];
    mq_cur[1] = mq_nxt[1];
    cur ^= 1;
  }

  // ---- epilogue: normalize (lacc rows match zacc rows), write Z ----------
#pragma unroll
  for (int m2 = 0; m2 < 2; ++m2)
#pragma unroll
    for (int r = 0; r < 4; ++r) {
      float inv = 1.0f / lacc[m2][r];
      int q = qt0 + w * 32 + m2 * 16 + row4 + r;
#pragma unroll
      for (int df = 0; df < 4; ++df) {
        int d = df * 16 + c16;
        Z[(size_t)(b * kSQ + q) * kDIM + h * 64 + d] =
            (_Float16)(zacc[m2][df][r] * inv);
      }
    }
}

// -------------------------------------------------------------------------
extern "C" void kernel_launch(void* const* d_in, const int* in_sizes, int n_in,
                              void* d_out, int out_size, void* d_ws,
                              size_t ws_size, hipStream_t stream) {
  const float* x_q = (const float*)d_in[0];
  const float* x_k = (const float*)d_in[1];
  const float* x_v = (const float*)d_in[2];
  const int* mask = (const int*)d_in[3];
  const float* wq = (const float*)d_in[4];
  const float* bq = (const float*)d_in[5];
  const float* wk = (const float*)d_in[6];
  const float* bk = (const float*)d_in[7];
  const float* wv = (const float*)d_in[8];
  const float* bv = (const float*)d_in[9];
  const float* wo = (const float*)d_in[10];
  const float* bo = (const float*)d_in[11];

  const size_t W_ELEMS = (size_t)1024 * 1024;
  const size_t T_ELEMS = (size_t)kMTOT * kDIM;  // 8192*1024
  const size_t NEED = (4 * W_ELEMS + 5 * T_ELEMS) * 2 + (size_t)kBS * kSQ * (kSK / 32) * 4;
  if (ws_size < NEED) return;  // leaves output poisoned -> visible failure

  char* ws = (char*)d_ws;
  _Float16* Wq16 = (_Float16*)ws;
  _Float16* Wk16 = Wq16 + W_ELEMS;
  _Float16* Wv16 = Wk16 + W_ELEMS;
  _Float16* Wo16 = Wv16 + W_ELEMS;
  _Float16* Q16 = Wo16 + W_ELEMS;
  _Float16* K16 = Q16 + T_ELEMS;
  _Float16* V16 = K16 + T_ELEMS;
  _Float16* Vt16 = V16 + T_ELEMS;
  _Float16* Z16 = Vt16 + T_ELEMS;
  unsigned* mbits = (unsigned*)(Z16 + T_ELEMS);

  prep_kernel<<<4096, 256, 0, stream>>>(mask, mbits, wq, wk, wv, wo,
                                        Wq16, Wk16, Wv16, Wo16);

  gemm_qkv_kernel<<<1536, 256, 0, stream>>>(x_q, x_k, x_v, Wq16, Wk16, Wv16,
                                            bq, bk, bv, Q16, K16, V16);

  transpose_v_kernel<<<2048, 256, 0, stream>>>(V16, Vt16);

  attn_kernel<<<1024, 256, 0, stream>>>(Q16, K16, Vt16, mbits, Z16);

  gemm_o_kernel<<<512, 256, 0, stream>>>(Z16, Wo16, bo, (float*)d_out);
}

// Round 18
// 255.984 us; speedup vs baseline: 1.1286x; 1.0040x over previous
//
#include <hip/hip_runtime.h>

#define DEVINL __device__ __forceinline__

typedef _Float16 half8 __attribute__((ext_vector_type(8)));
typedef _Float16 half4 __attribute__((ext_vector_type(4)));
typedef __fp16 fp16x2 __attribute__((ext_vector_type(2)));
typedef float f32x4 __attribute__((ext_vector_type(4)));
typedef float float4v __attribute__((ext_vector_type(4)));

static constexpr int kDIM = 1024;
static constexpr int kHEADS = 16;
static constexpr int kHD = 64;
static constexpr int kBS = 4;
static constexpr int kSQ = 2048;
static constexpr int kSK = 2048;
static constexpr int kMTOT = kBS * kSQ;  // 8192

DEVINL void async_copy16(void* lds, const void* g) {
  __builtin_amdgcn_global_load_lds(
      (__attribute__((address_space(1))) unsigned int*)(g),
      (__attribute__((address_space(3))) unsigned int*)(lds), 16, 0, 0);
}

DEVINL unsigned pkrtz_u32(float a, float b) {
  fp16x2 h = __builtin_amdgcn_cvt_pkrtz(a, b);
  unsigned u;
  __builtin_memcpy(&u, &h, 4);
  return u;
}

// ---------------- prep: mask bit-packing + weight f32->f16 (one launch) ---
__global__ void prep_kernel(const int* __restrict__ mask,
                            unsigned* __restrict__ bits,
                            const float* __restrict__ s0, const float* __restrict__ s1,
                            const float* __restrict__ s2, const float* __restrict__ s3,
                            _Float16* __restrict__ d0, _Float16* __restrict__ d1,
                            _Float16* __restrict__ d2, _Float16* __restrict__ d3) {
  int bid = blockIdx.x;
  if (bid < 2048) {
    int t = bid * 256 + threadIdx.x;  // word index
    const int4* p = (const int4*)(mask + (size_t)t * 32);
    unsigned w = 0;
#pragma unroll
    for (int j = 0; j < 8; ++j) {
      int4 v = p[j];
      w |= (v.x != 0 ? 1u : 0u) << (j * 4);
      w |= (v.y != 0 ? 1u : 0u) << (j * 4 + 1);
      w |= (v.z != 0 ? 1u : 0u) << (j * 4 + 2);
      w |= (v.w != 0 ? 1u : 0u) << (j * 4 + 3);
    }
    bits[t] = w;
  } else {
    int cb = bid - 2048;
    int which = cb >> 9;  // 512 blocks per 1M-elem matrix
    const float* s = which == 0 ? s0 : which == 1 ? s1 : which == 2 ? s2 : s3;
    _Float16* d = which == 0 ? d0 : which == 1 ? d1 : which == 2 ? d2 : d3;
    int j = ((cb & 511) * 256 + threadIdx.x) * 8;
    float4v a0 = *(const float4v*)(s + j);
    float4v a1 = *(const float4v*)(s + j + 4);
    half8 h;
    h[0] = (_Float16)a0[0]; h[1] = (_Float16)a0[1];
    h[2] = (_Float16)a0[2]; h[3] = (_Float16)a0[3];
    h[4] = (_Float16)a1[0]; h[5] = (_Float16)a1[1];
    h[6] = (_Float16)a1[2]; h[7] = (_Float16)a1[3];
    *(half8*)(d + j) = h;
  }
}

// ---------------- GEMM body: C[M,N] = A[M,K] @ B[N,K]^T + bias ------------
// 128x128 tile, BK=64, 4 waves (2x2), single buf, bm-fastest bid (XCD affine).
template <bool A_F32, bool OUT_F16>
DEVINL void gemm_body(const void* __restrict__ Aptr,
                      const _Float16* __restrict__ B,
                      const float* __restrict__ bias,
                      void* __restrict__ Cptr, int N, int K, int bid,
                      _Float16* As, _Float16* Bs) {
  const int tid = threadIdx.x;
  const int lane = tid & 63;
  const int w = tid >> 6;
  const int wr = w >> 1, wc = w & 1;
  const int bm0 = (bid & 63) << 7;  // M-tile fastest -> XCD = bm%8
  const int bn0 = (bid >> 6) << 7;
  const int c16 = lane & 15;
  const int hi4 = lane >> 4;

  f32x4 acc[4][4] = {};

  for (int k0 = 0; k0 < K; k0 += 64) {
    __syncthreads();
    // ---- stage A tile [128][64] f16, rows 128B, 8 segs, xor (row&7) ------
    if (A_F32) {
      const float* A32 = (const float*)Aptr;
#pragma unroll
      for (int i = 0; i < 4; ++i) {
        int c = i * 256 + tid;
        int row = c >> 3, seg = c & 7;
        int gseg = seg ^ (row & 7);
        const float* src = A32 + (size_t)(bm0 + row) * K + k0 + gseg * 8;
        float4v a0 = *(const float4v*)src;
        float4v a1 = *(const float4v*)(src + 4);
        half8 h;
        h[0] = (_Float16)a0[0]; h[1] = (_Float16)a0[1];
        h[2] = (_Float16)a0[2]; h[3] = (_Float16)a0[3];
        h[4] = (_Float16)a1[0]; h[5] = (_Float16)a1[1];
        h[6] = (_Float16)a1[2]; h[7] = (_Float16)a1[3];
        *(half8*)((char*)As + c * 16) = h;
      }
    } else {
      const _Float16* A16 = (const _Float16*)Aptr;
#pragma unroll
      for (int i = 0; i < 4; ++i) {
        int c = i * 256 + tid;
        int row = c >> 3, seg = c & 7;
        int gseg = seg ^ (row & 7);
        async_copy16((char*)As + i * 4096 + w * 1024,
                     A16 + (size_t)(bm0 + row) * K + k0 + gseg * 8);
      }
    }
    // ---- stage B tile ----------------------------------------------------
#pragma unroll
    for (int i = 0; i < 4; ++i) {
      int c = i * 256 + tid;
      int row = c >> 3, seg = c & 7;
      int gseg = seg ^ (row & 7);
      async_copy16((char*)Bs + i * 4096 + w * 1024,
                   B + (size_t)(bn0 + row) * K + k0 + gseg * 8);
    }
    __syncthreads();
    // ---- fragments + MFMA, per kf half (K=32 each) -----------------------
#pragma unroll
    for (int kf = 0; kf < 2; ++kf) {
      half8 af[4], bf[4];
#pragma unroll
      for (int m = 0; m < 4; ++m) {
        int row = wr * 64 + m * 16 + c16;
        int off = row * 128 + (((kf * 4 + hi4) << 4) ^ ((row & 7) << 4));
        af[m] = *(const half8*)((const char*)As + off);
      }
#pragma unroll
      for (int n = 0; n < 4; ++n) {
        int row = wc * 64 + n * 16 + c16;
        int off = row * 128 + (((kf * 4 + hi4) << 4) ^ ((row & 7) << 4));
        bf[n] = *(const half8*)((const char*)Bs + off);
      }
#pragma unroll
      for (int m = 0; m < 4; ++m)
#pragma unroll
        for (int n = 0; n < 4; ++n)
          acc[m][n] =
              __builtin_amdgcn_mfma_f32_16x16x32_f16(af[m], bf[n], acc[m][n], 0, 0, 0);
    }
  }
  // ---- epilogue: bias + store ------------------------------------------
#pragma unroll
  for (int n = 0; n < 4; ++n) {
    int col = bn0 + wc * 64 + n * 16 + c16;
    float bv = bias[col];
#pragma unroll
    for (int m = 0; m < 4; ++m) {
      int row0 = bm0 + wr * 64 + m * 16 + (hi4 << 2);
#pragma unroll
      for (int r = 0; r < 4; ++r) {
        float v = acc[m][n][r] + bv;
        if (OUT_F16)
          ((_Float16*)Cptr)[(size_t)(row0 + r) * N + col] = (_Float16)v;
        else
          ((float*)Cptr)[(size_t)(row0 + r) * N + col] = v;
      }
    }
  }
}

// Q/K/V projections in ONE launch: grid 1536, which = bid>>9.
__launch_bounds__(256, 2)
__global__ void gemm_qkv_kernel(const float* __restrict__ xq,
                                const float* __restrict__ xk,
                                const float* __restrict__ xv,
                                const _Float16* __restrict__ Wq,
                                const _Float16* __restrict__ Wk,
                                const _Float16* __restrict__ Wv,
                                const float* __restrict__ bq,
                                const float* __restrict__ bk,
                                const float* __restrict__ bv,
                                _Float16* __restrict__ Q16,
                                _Float16* __restrict__ K16,
                                _Float16* __restrict__ V16) {
  __shared__ __align__(16) _Float16 As[128 * 64];
  __shared__ __align__(16) _Float16 Bs[128 * 64];
  int which = blockIdx.x >> 9;
  int bid = blockIdx.x & 511;
  const float* A = which == 0 ? xq : which == 1 ? xk : xv;
  const _Float16* B = which == 0 ? Wq : which == 1 ? Wk : Wv;
  const float* bias = which == 0 ? bq : which == 1 ? bk : bv;
  _Float16* C = which == 0 ? Q16 : which == 1 ? K16 : V16;
  gemm_body<true, true>(A, B, bias, C, kDIM, kDIM, bid, As, Bs);
}

// O-projection (f16 A, f32 out), single launch.
__launch_bounds__(256, 2)
__global__ void gemm_o_kernel(const _Float16* __restrict__ Z16,
                              const _Float16* __restrict__ Wo,
                              const float* __restrict__ bo,
                              float* __restrict__ out) {
  __shared__ __align__(16) _Float16 As[128 * 64];
  __shared__ __align__(16) _Float16 Bs[128 * 64];
  gemm_body<false, false>(Z16, Wo, bo, out, kDIM, kDIM, blockIdx.x, As, Bs);
}

// ---------------- V transpose: V[(b s)][h*64+d] -> Vt[(b h d)][s] ---------
__global__ void transpose_v_kernel(const _Float16* __restrict__ V,
                                   _Float16* __restrict__ Vt) {
  __shared__ _Float16 tile[64][72];
  int bid = blockIdx.x;
  int bh = bid & 63;  // (b,h) fastest -> XCD = bh%8 (matches attn)
  int b = bh >> 4, h = bh & 15;
  int s0 = (bid >> 6) * 64;
  int tid = threadIdx.x;
  {
    int s = tid >> 2, dseg = tid & 3;
    const half8* src =
        (const half8*)(V + (size_t)(b * kSK + s0 + s) * kDIM + h * 64 + dseg * 16);
    half8 v0 = src[0], v1 = src[1];
#pragma unroll
    for (int j = 0; j < 8; ++j) {
      tile[s][dseg * 16 + j] = v0[j];
      tile[s][dseg * 16 + 8 + j] = v1[j];
    }
  }
  __syncthreads();
  {
    int d = tid >> 2, sseg = tid & 3;
    half8 o0, o1;
#pragma unroll
    for (int j = 0; j < 8; ++j) {
      o0[j] = tile[sseg * 16 + j][d];
      o1[j] = tile[sseg * 16 + 8 + j][d];
    }
    half8* dst = (half8*)(Vt + ((size_t)(bh * 64 + d)) * kSK + s0 + sseg * 16);
    dst[0] = o0;
    dst[1] = o1;
  }
}

// ---------------- flash attention (QBLK=256, 4 waves x 64 q-rows) ---------
// block: 256 q-rows, 4 waves (64 rows each: m2=0..3), KT=64 keys/iter.
// Same barrier/staging structure as the proven 128-row version, but each
// staged K/V tile serves 2x q-rows -> barrier periods and K/V fetch halve;
// each kb LDS read feeds 4 MFMAs. Ps stays 128x144 via two m2-pair passes
// (r7-proven wave-private reuse: rows w*32+(m2&1)*16+c16, strict sm->PV).
// LDS = 32768 + 18432 = 51200 (same as proven) -> 2 blocks/CU.
__launch_bounds__(256, 2)
__global__ void attn_kernel(const _Float16* __restrict__ Q,
                            const _Float16* __restrict__ K,
                            const _Float16* __restrict__ Vt,
                            const unsigned* __restrict__ maskbits,
                            _Float16* __restrict__ Z) {
  __shared__ __align__(16) char smem[32768 + 128 * 144];  // 2 KV bufs + Ps
  char* Ps = smem + 32768;  // [128] rows, stride 144B
  const int tid = threadIdx.x, lane = tid & 63, w = tid >> 6;
  const int bid = blockIdx.x;
  const int hb = bid & 63;  // (b,h) fastest -> XCD = hb%8
  const int b = hb >> 4, h = hb & 15;
  const int qt0 = (bid >> 6) * 256;
  const int c16 = lane & 15;
  const int hi4 = lane >> 4;
  const int row4 = hi4 << 2;
  const unsigned* mb = maskbits + (size_t)b * kSQ * (kSK / 32);

  // ---- stage Q tile [256][64] f16 = 32KB over the K/V dbuf region --------
#pragma unroll
  for (int i = 0; i < 8; ++i) {
    int c = i * 256 + tid;
    int row = c >> 3, seg = c & 7;
    int gseg = seg ^ (row & 7);
    async_copy16(smem + i * 4096 + w * 1024,
                 Q + (size_t)(b * kSQ + qt0 + row) * kDIM + h * 64 + gseg * 8);
  }
  __syncthreads();
  half8 qf[4][2];
#pragma unroll
  for (int m2 = 0; m2 < 4; ++m2)
#pragma unroll
    for (int kf = 0; kf < 2; ++kf) {
      int row = w * 64 + m2 * 16 + c16;
      int off = row * 128 + (((kf * 4 + hi4) << 4) ^ ((row & 7) << 4));
      qf[m2][kf] = *(const half8*)(smem + off);
      qf[m2][kf] *= (_Float16)0.18033688f;  // 0.125 * log2(e)
    }
  __syncthreads();  // all waves consumed Q before K/V overwrite

  // stage helper: K[64][64] + Vt[64][64] into buf (bufoff = 0 or 16384)
  auto stage_kv = [&](int bufoff, int ktt) {
#pragma unroll
    for (int i = 0; i < 2; ++i) {
      int c = i * 256 + tid;
      int row = c >> 3, seg = c & 7;
      int gseg = seg ^ (row & 7);
      async_copy16(smem + bufoff + i * 4096 + w * 1024,
                   K + (size_t)(b * kSK + ktt + row) * kDIM + h * 64 + gseg * 8);
    }
#pragma unroll
    for (int i = 0; i < 2; ++i) {
      int c = i * 256 + tid;
      int row = c >> 3, seg = c & 7;
      int gseg = seg ^ (row & 7);
      async_copy16(smem + bufoff + 8192 + i * 4096 + w * 1024,
                   Vt + (size_t)((b * kHEADS + h) * kHD + row) * kSK + ktt + gseg * 8);
    }
  };

  // prologue: tile 0
  unsigned long long mq_cur[4], mq_nxt[4];
  stage_kv(0, 0);
#pragma unroll
  for (int m2 = 0; m2 < 4; ++m2) {
    int q = qt0 + w * 64 + m2 * 16 + c16;
    mq_cur[m2] = *(const unsigned long long*)(mb + (size_t)q * (kSK / 32));
  }
  asm volatile("s_waitcnt vmcnt(0)" ::: "memory");
  __builtin_amdgcn_s_barrier();
  asm volatile("" ::: "memory");

  f32x4 zacc[4][4] = {};
  f32x4 lacc[4] = {};
  half8 ones8;
#pragma unroll
  for (int j = 0; j < 8; ++j) ones8[j] = (_Float16)1.0f;

  int cur = 0;
  for (int kt = 0; kt < kSK; kt += 64) {
    // ---- prefetch next tile ---------------------------------------------
    if (kt + 64 < kSK) {
      stage_kv((cur ^ 1) * 16384, kt + 64);
#pragma unroll
      for (int m2 = 0; m2 < 4; ++m2) {
        int q = qt0 + w * 64 + m2 * 16 + c16;
        mq_nxt[m2] = *(const unsigned long long*)(mb + (size_t)q * (kSK / 32) +
                                                  ((kt + 64) >> 5));
      }
    }
    const char* bufK = smem + cur * 16384;
    const char* bufV = bufK + 8192;

    // ---- QK^T swapped: lane q=c16, key = n*16 + hi4*4 + r; kb reused x4 --
    f32x4 s[4][4] = {};
    __builtin_amdgcn_s_setprio(1);
#pragma unroll
    for (int kf = 0; kf < 2; ++kf)
#pragma unroll
      for (int n = 0; n < 4; ++n) {
        int key = n * 16 + c16;
        half8 kb = *(const half8*)(bufK + key * 128 +
                                   (((kf * 4 + hi4) << 4) ^ ((key & 7) << 4)));
#pragma unroll
        for (int m2 = 0; m2 < 4; ++m2)
          s[m2][n] = __builtin_amdgcn_mfma_f32_16x16x32_f16(kb, qf[m2][kf], s[m2][n], 0, 0, 0);
      }
    __builtin_amdgcn_s_setprio(0);

    // ---- two m2-pair passes through the shared Ps region -----------------
#pragma unroll
    for (int p = 0; p < 2; ++p) {
      // softmax: P = 2^s AND sbfe-mask (no max; s bounded)
#pragma unroll
      for (int mi = 0; mi < 2; ++mi) {
        const int m2 = p * 2 + mi;
        unsigned lo = (unsigned)(mq_cur[m2] >> (hi4 * 4));
        unsigned hh = (unsigned)(mq_cur[m2] >> (hi4 * 4 + 32));
        int q_ps = w * 32 + mi * 16 + c16;
#pragma unroll
        for (int n = 0; n < 4; ++n) {
          unsigned sel = (n < 2) ? lo : hh;
          const int base = (n & 1) * 16;
          float pp[4];
#pragma unroll
          for (int r = 0; r < 4; ++r) {
            float pv = __builtin_exp2f(s[m2][n][r]);
            int msk = __builtin_amdgcn_sbfe((int)sel, base + r, 1);  // 0/-1
            pv = __uint_as_float(__float_as_uint(pv) & (unsigned)msk);
            pp[r] = pv;
          }
          uint2 pw = {pkrtz_u32(pp[0], pp[1]), pkrtz_u32(pp[2], pp[3])};
          *(uint2*)(Ps + q_ps * 144 + n * 32 + hi4 * 8) = pw;
        }
      }
      // PV for this m2-pair + l-accum (ones-MFMA)
      __builtin_amdgcn_s_setprio(1);
#pragma unroll
      for (int kf2 = 0; kf2 < 2; ++kf2) {
        half8 vb[4];
#pragma unroll
        for (int df = 0; df < 4; ++df) {
          int d = df * 16 + c16;
          vb[df] = *(const half8*)(bufV + d * 128 +
                                   (((kf2 * 4 + hi4) << 4) ^ ((d & 7) << 4)));
        }
#pragma unroll
        for (int mi = 0; mi < 2; ++mi) {
          const int m2 = p * 2 + mi;
          int q_ps = w * 32 + mi * 16 + c16;
          half8 pa = *(const half8*)(Ps + q_ps * 144 + (kf2 * 4 + hi4) * 16);
          lacc[m2] = __builtin_amdgcn_mfma_f32_16x16x32_f16(pa, ones8, lacc[m2], 0, 0, 0);
#pragma unroll
          for (int df = 0; df < 4; ++df)
            zacc[m2][df] =
                __builtin_amdgcn_mfma_f32_16x16x32_f16(pa, vb[df], zacc[m2][df], 0, 0, 0);
        }
      }
      __builtin_amdgcn_s_setprio(0);
    }

    asm volatile("s_waitcnt vmcnt(0)" ::: "memory");
    __builtin_amdgcn_s_barrier();
    asm volatile("" ::: "memory");
#pragma unroll
    for (int m2 = 0; m2 < 4; ++m2) mq_cur[m2] = mq_nxt[m2];
    cur ^= 1;
  }

  // ---- epilogue: normalize (lacc rows match zacc rows), write Z ----------
#pragma unroll
  for (int m2 = 0; m2 < 4; ++m2)
#pragma unroll
    for (int r = 0; r < 4; ++r) {
      float inv = 1.0f / lacc[m2][r];
      int q = qt0 + w * 64 + m2 * 16 + row4 + r;
#pragma unroll
      for (int df = 0; df < 4; ++df) {
        int d = df * 16 + c16;
        Z[(size_t)(b * kSQ + q) * kDIM + h * 64 + d] =
            (_Float16)(zacc[m2][df][r] * inv);
      }
    }
}

// -------------------------------------------------------------------------
extern "C" void kernel_launch(void* const* d_in, const int* in_sizes, int n_in,
                              void* d_out, int out_size, void* d_ws,
                              size_t ws_size, hipStream_t stream) {
  const float* x_q = (const float*)d_in[0];
  const float* x_k = (const float*)d_in[1];
  const float* x_v = (const float*)d_in[2];
  const int* mask = (const int*)d_in[3];
  const float* wq = (const float*)d_in[4];
  const float* bq = (const float*)d_in[5];
  const float* wk = (const float*)d_in[6];
  const float* bk = (const float*)d_in[7];
  const float* wv = (const float*)d_in[8];
  const float* bv = (const float*)d_in[9];
  const float* wo = (const float*)d_in[10];
  const float* bo = (const float*)d_in[11];

  const size_t W_ELEMS = (size_t)1024 * 1024;
  const size_t T_ELEMS = (size_t)kMTOT * kDIM;  // 8192*1024
  const size_t NEED = (4 * W_ELEMS + 5 * T_ELEMS) * 2 + (size_t)kBS * kSQ * (kSK / 32) * 4;
  if (ws_size < NEED) return;  // leaves output poisoned -> visible failure

  char* ws = (char*)d_ws;
  _Float16* Wq16 = (_Float16*)ws;
  _Float16* Wk16 = Wq16 + W_ELEMS;
  _Float16* Wv16 = Wk16 + W_ELEMS;
  _Float16* Wo16 = Wv16 + W_ELEMS;
  _Float16* Q16 = Wo16 + W_ELEMS;
  _Float16* K16 = Q16 + T_ELEMS;
  _Float16* V16 = K16 + T_ELEMS;
  _Float16* Vt16 = V16 + T_ELEMS;
  _Float16* Z16 = Vt16 + T_ELEMS;
  unsigned* mbits = (unsigned*)(Z16 + T_ELEMS);

  prep_kernel<<<4096, 256, 0, stream>>>(mask, mbits, wq, wk, wv, wo,
                                        Wq16, Wk16, Wv16, Wo16);

  gemm_qkv_kernel<<<1536, 256, 0, stream>>>(x_q, x_k, x_v, Wq16, Wk16, Wv16,
                                            bq, bk, bv, Q16, K16, V16);

  transpose_v_kernel<<<2048, 256, 0, stream>>>(V16, Vt16);

  attn_kernel<<<512, 256, 0, stream>>>(Q16, K16, Vt16, mbits, Z16);

  gemm_o_kernel<<<512, 256, 0, stream>>>(Z16, Wo16, bo, (float*)d_out);
}